// Round 7
// baseline (783.179 us; speedup 1.0000x reference)
//
#include <hip/hip_runtime.h>

// MLPP: 8x 256x256 GEMMs over gathered views of x[4,32,32,32,256] (fp32 in/out).
// pack -> k_att (att[t][pos][c] -> R2) -> k_hw (h+w summed -> hw_sum[t][pos][c] in d_out)
//      -> k_comb (c-GEMM + hw/att streams + W1 + residual -> x1_blk R1, pos-QUARTER blocks)
//      -> k_d (R1 -> xd R2) -> k_fin (R1,R2 -> d_out)
// k_hw: 1024 threads (16 waves) per tile, LDS 160K. k_comb: 64K LDS -> 2 blocks/CU.

typedef __attribute__((ext_vector_type(8))) short bf16x8;
typedef __attribute__((ext_vector_type(8))) unsigned short u16x8;
typedef __attribute__((ext_vector_type(4))) float f32x4;
typedef __attribute__((ext_vector_type(4))) unsigned short u16x4;
typedef unsigned short u16;
typedef unsigned int u32;

#define DEV __device__ __forceinline__

DEV u16 f2b(float f) {  // fp32 -> bf16 RNE
  union { float f; u32 u; } v; v.f = f;
  u32 r = v.u + 0x7FFFu + ((v.u >> 16) & 1u);
  return (u16)(r >> 16);
}
DEV float b2f(u16 b) {
  union { u32 u; float f; } v; v.u = ((u32)b) << 16; return v.f;
}

// 512B-pitch LDS tiles, XOR swizzle over 16B slots (32 slots/row).
DEV int lds_off(int row, int colByte) {
  return (row << 9) + (colByte ^ ((row & 31) << 4));
}
// 256B-pitch tiles (16 slots/row).
DEV int lds_off256(int row, int colByte) {
  return (row << 8) + (colByte ^ ((row & 15) << 4));
}
DEV bf16x8 ld_lds(const u16* lds, int row, int colByte) {
  return *(const bf16x8*)((const char*)lds + lds_off(row, colByte));
}
DEV bf16x8 ld_glb(const u16* g, int row, int kByte) {  // row-major [.][256] bf16
  return *(const bf16x8*)((const char*)g + (row << 9) + kByte);
}

template <int MI, int NJ>
DEV void zero_acc(f32x4 acc[MI][NJ]) {
#pragma unroll
  for (int i = 0; i < MI; ++i)
#pragma unroll
    for (int j = 0; j < NJ; ++j) {
      acc[i][j][0] = 0.f; acc[i][j][1] = 0.f; acc[i][j][2] = 0.f; acc[i][j][3] = 0.f;
    }
}

// D[m][n] = sum_k P[m][k] * Q[n][k], K=256. MI/NJ = 16x16 tiles per wave.
template <int MI, int NJ, typename LA, typename LB>
DEV void gemmT(LA loadA, LB loadB, f32x4 acc[MI][NJ]) {
#pragma unroll
  for (int kk = 0; kk < 8; ++kk) {
    bf16x8 a[MI], b[NJ];
#pragma unroll
    for (int i = 0; i < MI; ++i) a[i] = loadA(i, kk);
#pragma unroll
    for (int j = 0; j < NJ; ++j) b[j] = loadB(j, kk);
#pragma unroll
    for (int i = 0; i < MI; ++i)
#pragma unroll
      for (int j = 0; j < NJ; ++j)
        acc[i][j] = __builtin_amdgcn_mfma_f32_16x16x32_bf16(a[i], b[j], acc[i][j], 0, 0, 0);
  }
}

#define WAVE_SETUP                  \
  const int tid = threadIdx.x;      \
  const int lane = tid & 63;        \
  const int wave = tid >> 6;        \
  const int wm = wave >> 2;         \
  const int wn = wave & 3;          \
  const int lr = lane & 15;         \
  const int lk = lane >> 4;

// ---------- weight pack: WT[s][n*256+k] = W_s[k*256+n] (+I for s==7) ----------
__global__ void k_pack_all(const float* W0, const float* W1p, const float* W2p,
                           const float* W3p, const float* W4p, const float* W5p,
                           const float* W6p, const float* W7p, u16* __restrict__ WT) {
  int bi = blockIdx.x;
  int wsel = bi >> 8, n = bi & 255;
  const float* W;
  switch (wsel) {
    case 0: W = W0; break; case 1: W = W1p; break; case 2: W = W2p; break;
    case 3: W = W3p; break; case 4: W = W4p; break; case 5: W = W5p; break;
    case 6: W = W6p; break; default: W = W7p; break;
  }
  u16* dst = WT + wsel * 65536;
  int k0 = threadIdx.x * 4;
#pragma unroll
  for (int i = 0; i < 4; ++i) {
    int k = k0 + i;
    float v = W[k * 256 + n];
    if (wsel == 7 && k == n) v += 1.0f;
    dst[n * 256 + k] = f2b(v);
  }
}

// ---------- att: D[p][c] = sum_q Wa[q][p] X[q][c] (+b_attn[p]); c-half blocks ----------
__global__ __launch_bounds__(512, 4) void k_att(const float* __restrict__ x,
    const u16* __restrict__ WTattn, const float* __restrict__ b_attn,
    u16* __restrict__ att) {
  __shared__ alignas(16) u16 XT[32768];  // [c-half 128][q 256], 64 KiB
  WAVE_SETUP;
  const int ch = blockIdx.x & 1;
  const int t = blockIdx.x >> 1;
  const int d = t & 31, w1 = (t >> 5) & 1, h1 = (t >> 6) & 1, b = t >> 7;
  const int B0 = (((b * 32 + h1 * 16) * 32 + w1 * 16) * 32 + d) * 256;

  for (int i = tid; i < 8192; i += 512) {
    int q = i >> 5;
    int c4 = (i & 31) << 2;
    const float4 v = *(const float4*)(x + B0 + (q >> 4) * 262144 + (q & 15) * 8192 + ch * 128 + c4);
    XT[lds_off(c4 + 0, q * 2) >> 1] = f2b(v.x);
    XT[lds_off(c4 + 1, q * 2) >> 1] = f2b(v.y);
    XT[lds_off(c4 + 2, q * 2) >> 1] = f2b(v.z);
    XT[lds_off(c4 + 3, q * 2) >> 1] = f2b(v.w);
  }
  __syncthreads();

  f32x4 acc[8][2];
  zero_acc<8, 2>(acc);
  gemmT<8, 2>(
      [&](int i, int kk) { return ld_glb(WTattn, wm * 128 + i * 16 + lr, kk * 64 + lk * 16); },
      [&](int j, int kk) { return ld_lds(XT, wn * 32 + j * 16 + lr, kk * 64 + lk * 16); },
      acc);

  __syncthreads();  // XT dead; reuse as [p 256][c-half 128] bounce tile (256B pitch)
#pragma unroll
  for (int i = 0; i < 8; ++i)
#pragma unroll
    for (int j = 0; j < 2; ++j)
#pragma unroll
      for (int r = 0; r < 4; ++r) {
        int p = wm * 128 + i * 16 + lk * 4 + r;
        int cl = wn * 32 + j * 16 + lr;
        XT[lds_off256(p, cl * 2) >> 1] = f2b(acc[i][j][r] + b_attn[p]);
      }
  __syncthreads();
  u16* out = att + t * 65536;
  for (int i = tid; i < 4096; i += 512) {
    int p = i >> 4, sB = (i & 15) << 4;
    bf16x8 v = *(const bf16x8*)((const char*)XT + p * 256 + sB);
    int c8l = (sB ^ ((p & 15) << 4)) >> 1;
    *(bf16x8*)(out + p * 256 + ch * 128 + c8l) = v;
  }
}

// ---------- k_hw: h+w GEMMs, 16 waves, summed per 64-pos slab, stored hw_sum[t][pos][c] ----------
__global__ __launch_bounds__(1024, 4) void k_hw(const float* __restrict__ x,
    const u16* __restrict__ WTh, const u16* __restrict__ WTw, u16* __restrict__ hw_sum) {
  __shared__ alignas(16) u16 XS[65536];  // 128 KiB [pos][c]
  __shared__ alignas(16) u16 BB[16384];  // 32 KiB slab [posl 64][c 256]
  const int tid = threadIdx.x;
  const int lane = tid & 63;
  const int wv = tid >> 6;     // 0..15
  const int lr = lane & 15;
  const int lk = lane >> 4;
  const int t = blockIdx.x;
  const int d = t & 31, w1 = (t >> 5) & 1, h1 = (t >> 6) & 1, b = t >> 7;
  const int B0 = (((b * 32 + h1 * 16) * 32 + w1 * 16) * 32 + d) * 256;
  u16* out = hw_sum + t * 65536;

  for (int i = tid; i < 16384; i += 1024) {
    int pos = i >> 6, c4 = (i & 63) << 2;
    const float4 v = *(const float4*)(x + B0 + (pos >> 4) * 262144 + (pos & 15) * 8192 + c4);
    u16x4 pk;
    pk[0] = f2b(v.x); pk[1] = f2b(v.y); pk[2] = f2b(v.z); pk[3] = f2b(v.w);
    *(u16x4*)((char*)XS + lds_off(pos, c4 * 2)) = pk;
  }
  __syncthreads();

  for (int s = 0; s < 4; ++s) {
    // h chunk: nh in [64s,64s+64). Wave wv owns m-tile wv (16 rows), all 4 n-tiles.
    // A[mh][k] = XS[(k>>4)*16 + (mh&15)][(mh>>4)*16 + (k&15)], mh = wv*16+lr
    f32x4 hacc[1][4];
    zero_acc<1, 4>(hacc);
    gemmT<1, 4>(
        [&](int i, int kk) {
          int k = kk * 32 + lk * 8;
          return *(const bf16x8*)((const char*)XS +
                                  lds_off((k >> 4) * 16 + lr, wv * 32 + (k & 15) * 2));
        },
        [&](int j, int kk) { return ld_glb(WTh, s * 64 + j * 16 + lr, kk * 64 + lk * 16); },
        hacc);
    __syncthreads();  // prev slab's BB store reads done
    // element mh=wv*16+lk*4+r, nl=j*16+lr -> posl=j*16+lk*4+r, c=wv*16+lr
#pragma unroll
    for (int j = 0; j < 4; ++j)
#pragma unroll
      for (int r = 0; r < 4; ++r)
        BB[lds_off(j * 16 + lk * 4 + r, (wv * 16 + lr) * 2) >> 1] = f2b(hacc[0][j][r]);
    __syncthreads();

    // w chunk: mw rows with (mw&15) in [4s,4s+4). Wave: mt=wv>>2, nq=wv&3 (4 n-tiles each).
    // A[mloc][k] = XS[(4s+(mloc&3))*16 + (k>>4)][(mloc>>2)*16 + (k&15)], mloc=mt*16+lr
    f32x4 wacc[1][4];
    zero_acc<1, 4>(wacc);
    {
      const int mt = wv >> 2, nq = wv & 3;
      gemmT<1, 4>(
          [&](int i, int kk) {
            int k = kk * 32 + lk * 8;
            return *(const bf16x8*)((const char*)XS +
                lds_off((4 * s + (lr & 3)) * 16 + (k >> 4),
                        (mt * 4 + (lr >> 2)) * 32 + (k & 15) * 2));
          },
          [&](int j, int kk) { return ld_glb(WTw, (nq * 4 + j) * 16 + lr, kk * 64 + lk * 16); },
          wacc);
      // element: mloc=mt*16+lk*4+r, n=(nq*4+j)*16+lr -> posl=r*16+nq*4+j, c=(mt*4+lk)*16+lr
#pragma unroll
      for (int j = 0; j < 4; ++j)
#pragma unroll
        for (int r = 0; r < 4; ++r) {
          int idx = lds_off(r * 16 + nq * 4 + j, ((mt * 4 + lk) * 16 + lr) * 2) >> 1;
          BB[idx] = f2b(b2f(BB[idx]) + wacc[0][j][r]);
        }
    }
    __syncthreads();

    // store slab, sector-perfect
    for (int i2 = tid; i2 < 2048; i2 += 1024) {
      int posl = i2 >> 5, sB = (i2 & 31) << 4;
      bf16x8 v = *(const bf16x8*)((const char*)BB + posl * 512 + sB);
      int c8 = (sB ^ ((posl & 31) << 4)) >> 1;
      *(bf16x8*)(out + (s * 64 + posl) * 256 + c8) = v;
    }
  }
}

// ---------- k_comb: c-GEMM + (hw_sum,att streams) + W1 + residual -> x1_blk; pos-QUARTER ----------
__global__ __launch_bounds__(512, 4) void k_comb(const float* __restrict__ x,
    const u16* __restrict__ hw_sum, const u16* __restrict__ att,
    const float* __restrict__ bh, const float* __restrict__ bw, const float* __restrict__ bc,
    const u16* __restrict__ WTc, const u16* __restrict__ WT1, const float* __restrict__ b1,
    u16* __restrict__ x1_blk) {
  __shared__ alignas(16) u16 XS[16384];  // 32 KiB x tile [posl 64][c 256]
  __shared__ alignas(16) u16 BB[16384];  // 32 KiB work tile
  WAVE_SETUP;
  const int pq = blockIdx.x & 3;
  const int t = blockIdx.x >> 2;
  const int d = t & 31, w1 = (t >> 5) & 1, h1 = (t >> 6) & 1, b = t >> 7;
  const int B0 = (((b * 32 + h1 * 16) * 32 + w1 * 16) * 32 + d) * 256;
  const u16* hw_t = hw_sum + t * 65536;
  const u16* att_t = att + t * 65536;

  // stage XS (bf16) for this pos-quarter; x read ONCE
  for (int i = tid; i < 4096; i += 512) {
    int posl = i >> 6, c4 = (i & 63) << 2;
    int pos = pq * 64 + posl;
    const float4 v = *(const float4*)(x + B0 + (pos >> 4) * 262144 + (pos & 15) * 8192 + c4);
    u16x4 pk;
    pk[0] = f2b(v.x); pk[1] = f2b(v.y); pk[2] = f2b(v.z); pk[3] = f2b(v.w);
    *(u16x4*)((char*)XS + lds_off(posl, c4 * 2)) = pk;
  }
  __syncthreads();

  // c-GEMM: M=64 (wm: 2 tiles each), N=256 (wn: 4 tiles each)
  f32x4 acc[2][4];
  zero_acc<2, 4>(acc);
  gemmT<2, 4>(
      [&](int i, int kk) { return ld_lds(XS, wm * 32 + i * 16 + lr, kk * 64 + lk * 16); },
      [&](int j, int kk) { return ld_glb(WTc, wn * 64 + j * 16 + lr, kk * 64 + lk * 16); },
      acc);
  // BB = acc + bc + bh + bw
#pragma unroll
  for (int i = 0; i < 2; ++i) {
    int lh = pq * 4 + wm * 2 + i;  // (pq*64 + wm*32 + i*16 + ...) >> 4
#pragma unroll
    for (int j = 0; j < 4; ++j) {
      float bcv = bc[wn * 64 + j * 16 + lr];
#pragma unroll
      for (int r = 0; r < 4; ++r) {
        int posl = wm * 32 + i * 16 + lk * 4 + r;
        int n = wn * 64 + j * 16 + lr;
        float v = acc[i][j][r] + bcv + bh[lh * 16 + lr] + bw[(lk * 4 + r) * 16 + lr];
        BB[lds_off(posl, n * 2) >> 1] = f2b(v);
      }
    }
  }
  __syncthreads();

  // streamed: BB = (1+att) * (BB + hw_sum)
  for (int i2 = tid; i2 < 2048; i2 += 512) {
    int posl = i2 >> 5, c8 = (i2 & 31) << 3;
    int pos = pq * 64 + posl;
    u16x8 hv = *(const u16x8*)(hw_t + pos * 256 + c8);
    u16x8 av = *(const u16x8*)(att_t + pos * 256 + c8);
    u16x8* p = (u16x8*)((char*)BB + lds_off(posl, c8 * 2));
    u16x8 cur = *p, o;
#pragma unroll
    for (int j = 0; j < 8; ++j)
      o[j] = f2b((1.0f + b2f(av[j])) * (b2f(cur[j]) + b2f(hv[j])));
    *p = o;
  }
  __syncthreads();

  // W1-GEMM
  zero_acc<2, 4>(acc);
  gemmT<2, 4>(
      [&](int i, int kk) { return ld_lds(BB, wm * 32 + i * 16 + lr, kk * 64 + lk * 16); },
      [&](int j, int kk) { return ld_glb(WT1, wn * 64 + j * 16 + lr, kk * 64 + lk * 16); },
      acc);
  __syncthreads();
  // BB = acc + b1
#pragma unroll
  for (int i = 0; i < 2; ++i)
#pragma unroll
    for (int j = 0; j < 4; ++j) {
      float b1v = b1[wn * 64 + j * 16 + lr];
#pragma unroll
      for (int r = 0; r < 4; ++r) {
        int posl = wm * 32 + i * 16 + lk * 4 + r;
        int n = wn * 64 + j * 16 + lr;
        BB[lds_off(posl, n * 2) >> 1] = f2b(acc[i][j][r] + b1v);
      }
    }
  __syncthreads();

  // x1 = BB + x(bf16 from XS); wide store (t-blocked)
  u16* x1out = x1_blk + t * 65536;
  for (int i2 = tid; i2 < 2048; i2 += 512) {
    int posl = i2 >> 5, sB = (i2 & 31) << 4;
    bf16x8 v = *(const bf16x8*)((const char*)BB + posl * 512 + sB);
    bf16x8 xv = *(const bf16x8*)((const char*)XS + posl * 512 + sB);
    int c8 = (sB ^ ((posl & 31) << 4)) >> 1;
    u16x8 o;
#pragma unroll
    for (int j = 0; j < 8; ++j) o[j] = f2b(b2f((u16)v[j]) + b2f((u16)xv[j]));
    *(u16x8*)(x1out + (pq * 64 + posl) * 256 + c8) = o;
  }
}

// ---------- d-block gather GEMM (wlo-half blocks) ----------
__global__ __launch_bounds__(512, 2) void k_d(const u16* __restrict__ x1_blk,
    const u16* __restrict__ WTd, const float* __restrict__ bd, u16* __restrict__ xd) {
  __shared__ alignas(16) u16 XS[32768];  // [R 128][c 256]: R=(wloLoc,ld)
  WAVE_SETUP;
  const int bid = blockIdx.x;
  const int wh = bid & 1, d1 = (bid >> 1) & 1, wb = (bid >> 2) & 1,
            h = (bid >> 3) & 31, b = bid >> 8;
  const int tbase = b * 128 + (h >> 4) * 64 + wb * 32 + d1 * 16;
  const int posbase = (h & 15) * 16 + wh * 8;

  for (int i = tid; i < 4096; i += 512) {
    int Rl = i >> 5;              // wloLoc*16 + ld
    int c8 = (i & 31) << 3;
    int wloLoc = Rl >> 4, ld = Rl & 15;
    const u16x8 v = *(const u16x8*)(x1_blk + (size_t)(tbase + ld) * 65536 +
                                    (posbase + wloLoc) * 256 + c8);
    *(u16x8*)((char*)XS + lds_off(Rl, c8 * 2)) = v;
  }
  __syncthreads();

  f32x4 acc[4][4];
  zero_acc<4, 4>(acc);
  // m=(wloLoc,lc) k=(ld,g): A[m][k] = XS[(m>>4)*16+ld][lc*16+g]
  gemmT<4, 4>(
      [&](int i, int kk) {
        int k = kk * 32 + lk * 8;
        int khi = k >> 4, kloB = (k & 15) * 2;
        int mt = wm * 4 + i;
        return *(const bf16x8*)((const char*)XS + lds_off(mt * 16 + khi, lr * 32 + kloB));
      },
      [&](int j, int kk) { return ld_glb(WTd, wn * 64 + j * 16 + lr, kk * 64 + lk * 16); },
      acc);
  __syncthreads();
  // bounce: (mloc,n) -> row=(mloc>>4)*16+(n>>4), col=(mloc&15)*16+(n&15)
#pragma unroll
  for (int i = 0; i < 4; ++i)
#pragma unroll
    for (int j = 0; j < 4; ++j)
#pragma unroll
      for (int r = 0; r < 4; ++r) {
        int mloc = wm * 64 + i * 16 + lk * 4 + r;
        int n = wn * 64 + j * 16 + lr;
        int row = ((mloc >> 4) << 4) + (n >> 4);
        int col = ((mloc & 15) << 4) + (n & 15);
        XS[lds_off(row, col * 2) >> 1] = f2b(acc[i][j][r] + bd[n]);
      }
  __syncthreads();
  const int B0d = (((b * 32 + h) * 32 + wb * 16) * 32 + d1 * 16) * 256;
  for (int i = tid; i < 4096; i += 512) {
    int Rl = i >> 5, sB = (i & 31) << 4;
    bf16x8 v = *(const bf16x8*)((const char*)XS + Rl * 512 + sB);
    int c8 = (sB ^ ((Rl & 31) << 4)) >> 1;
    *(bf16x8*)(xd + B0d + (wh * 8 + (Rl >> 4)) * 8192 + (Rl & 15) * 256 + c8) = v;
  }
}

// ---------- fin: x2 = x1 + xd*W2 + b2; out = x2*(W3+I) + b3 (pos-half blocks) ----------
__global__ __launch_bounds__(512, 2) void k_fin(const u16* __restrict__ x1_blk,
    const u16* __restrict__ xd, const u16* __restrict__ WT2, const u16* __restrict__ WT3p,
    const float* __restrict__ b2, const float* __restrict__ b3, float* __restrict__ outp) {
  __shared__ alignas(16) u16 X2[32768];  // [128][256] bf16; later f32 bounce [64][256]
  WAVE_SETUP;
  const int ph = blockIdx.x & 1;
  const int vt = blockIdx.x >> 1;
  const int b = vt >> 7, h = (vt >> 2) & 31, w_hi = vt & 3;
  const size_t base = (size_t)vt * 65536;

  // stage x1 rows into X2 (wide); x1_blk is t-blocked
  for (int i = tid; i < 4096; i += 512) {
    int Rl = i >> 5, c8 = (i & 31) << 3;
    int rglob = ph * 128 + Rl;
    int w = w_hi * 8 + (rglob >> 5), d = rglob & 31;
    int t = b * 128 + (h >> 4) * 64 + (w >> 4) * 32 + d;
    int pos = (h & 15) * 16 + (w & 15);
    const u16x8 v = *(const u16x8*)(x1_blk + (size_t)t * 65536 + pos * 256 + c8);
    *(u16x8*)((char*)X2 + lds_off(Rl, c8 * 2)) = v;
  }

  // GEMM1: xd * W2 (A from global)
  const u16* xd_t = xd + base;
  f32x4 acc[4][4];
  zero_acc<4, 4>(acc);
  gemmT<4, 4>(
      [&](int i, int kk) { return ld_glb(xd_t, ph * 128 + wm * 64 + i * 16 + lr, kk * 64 + lk * 16); },
      [&](int j, int kk) { return ld_glb(WT2, wn * 64 + j * 16 + lr, kk * 64 + lk * 16); },
      acc);
  __syncthreads();

  // X2 = bf16(x1 + acc + b2)
#pragma unroll
  for (int i = 0; i < 4; ++i)
#pragma unroll
    for (int j = 0; j < 4; ++j)
#pragma unroll
      for (int r = 0; r < 4; ++r) {
        int mloc = wm * 64 + i * 16 + lk * 4 + r;
        int n = wn * 64 + j * 16 + lr;
        int off = lds_off(mloc, n * 2) >> 1;
        X2[off] = f2b(b2f(X2[off]) + acc[i][j][r] + b2[n]);
      }
  __syncthreads();

  // GEMM2: X2 * (W3+I)
  zero_acc<4, 4>(acc);
  gemmT<4, 4>(
      [&](int i, int kk) { return ld_lds(X2, wm * 64 + i * 16 + lr, kk * 64 + lk * 16); },
      [&](int j, int kk) { return ld_glb(WT3p, wn * 64 + j * 16 + lr, kk * 64 + lk * 16); },
      acc);

  // fp32 output via 2-round LDS bounce (64 rows each), float4 stores
  float* X2f = (float*)X2;
#pragma unroll
  for (int half = 0; half < 2; ++half) {
    __syncthreads();
    if (wm == half) {
#pragma unroll
      for (int i = 0; i < 4; ++i)
#pragma unroll
        for (int j = 0; j < 4; ++j)
#pragma unroll
          for (int r = 0; r < 4; ++r) {
            int row = i * 16 + lk * 4 + r;
            int n = wn * 64 + j * 16 + lr;
            X2f[row * 256 + n] = acc[i][j][r] + b3[n];
          }
    }
    __syncthreads();
    for (int i = tid; i < 4096; i += 512) {
      int row = i >> 6, c4 = (i & 63) << 2;
      f32x4 v = *(const f32x4*)(X2f + row * 256 + c4);
      *(f32x4*)(outp + base + (size_t)(ph * 128 + half * 64 + row) * 256 + c4) = v;
    }
  }
}

extern "C" void kernel_launch(void* const* d_in, const int* in_sizes, int n_in,
                              void* d_out, int out_size, void* d_ws, size_t ws_size,
                              hipStream_t stream) {
  (void)in_sizes; (void)n_in; (void)out_size; (void)ws_size;
  const float* x      = (const float*)d_in[0];
  const float* W_h    = (const float*)d_in[1];
  const float* b_h    = (const float*)d_in[2];
  const float* W_w    = (const float*)d_in[3];
  const float* b_w    = (const float*)d_in[4];
  const float* W_c    = (const float*)d_in[5];
  const float* b_c    = (const float*)d_in[6];
  const float* W_d    = (const float*)d_in[7];
  const float* b_d    = (const float*)d_in[8];
  const float* W_attn = (const float*)d_in[9];
  const float* b_attn = (const float*)d_in[10];
  const float* W_1    = (const float*)d_in[11];
  const float* b_1    = (const float*)d_in[12];
  const float* W_2    = (const float*)d_in[13];
  const float* b_2    = (const float*)d_in[14];
  const float* W_3    = (const float*)d_in[15];
  const float* b_3    = (const float*)d_in[16];
  float* outp = (float*)d_out;

  u16* WT = (u16*)d_ws;             // 8 * 65536 bf16 (1 MiB)
  u16* R1 = WT + 8 * 65536;         // 64 MiB: x1_blk (t-blocked bf16)
  u16* R2 = R1 + 33554432;          // 64 MiB: att scratch -> xd
  u16* HWS = (u16*)d_out;           // hw_sum lives in d_out until k_comb; k_fin overwrites

  // slots: 0:h 1:w 2:c 3:attn 4:W1 5:Wd 6:W2 7:W3(+I)
  k_pack_all<<<2048, 64, 0, stream>>>(W_h, W_w, W_c, W_attn, W_1, W_d, W_2, W_3, WT);

  k_att <<<1024, 512, 0, stream>>>(x, WT + 3 * 65536, b_attn, R2);
  k_hw  <<<512, 1024, 0, stream>>>(x, WT + 0 * 65536, WT + 1 * 65536, HWS);
  k_comb<<<2048, 512, 0, stream>>>(x, HWS, R2, b_h, b_w, b_c,
                                   WT + 2 * 65536, WT + 4 * 65536, b_1, R1);
  k_d   <<<1024, 512, 0, stream>>>(R1, WT + 5 * 65536, b_d, R2);
  k_fin <<<1024, 512, 0, stream>>>(R1, R2, WT + 6 * 65536, WT + 7 * 65536, b_2, b_3, outp);
}

// Round 8
// 604.129 us; speedup vs baseline: 1.2964x; 1.2964x over previous
//
#include <hip/hip_runtime.h>

// MLPP: 8x 256x256 GEMMs over gathered views of x[4,32,32,32,256] (fp32 in/out).
// pack -> k_att (att[t][pos][c] -> R2) -> k_hw (h_out, w_out streams in d_out; each
// weight read ONCE per block) -> k_comb (c-GEMM + h/w/att streams + W1 + residual -> x1 R1)
//      -> k_d (R1 -> xd R2) -> k_fin (R1,R2 -> d_out)
// All pure streams use non-temporal loads/stores so weights stay L2-resident.

typedef __attribute__((ext_vector_type(8))) short bf16x8;
typedef __attribute__((ext_vector_type(8))) unsigned short u16x8;
typedef __attribute__((ext_vector_type(4))) float f32x4;
typedef __attribute__((ext_vector_type(4))) unsigned short u16x4;
typedef unsigned short u16;
typedef unsigned int u32;

#define DEV __device__ __forceinline__

DEV u16 f2b(float f) {  // fp32 -> bf16 RNE
  union { float f; u32 u; } v; v.f = f;
  u32 r = v.u + 0x7FFFu + ((v.u >> 16) & 1u);
  return (u16)(r >> 16);
}
DEV float b2f(u16 b) {
  union { u32 u; float f; } v; v.u = ((u32)b) << 16; return v.f;
}

// 512B-pitch LDS tiles, XOR swizzle over 16B slots (32 slots/row).
DEV int lds_off(int row, int colByte) {
  return (row << 9) + (colByte ^ ((row & 31) << 4));
}
// 256B-pitch tiles (16 slots/row).
DEV int lds_off256(int row, int colByte) {
  return (row << 8) + (colByte ^ ((row & 15) << 4));
}
DEV bf16x8 ld_lds(const u16* lds, int row, int colByte) {
  return *(const bf16x8*)((const char*)lds + lds_off(row, colByte));
}
DEV bf16x8 ld_glb(const u16* g, int row, int kByte) {  // row-major [.][256] bf16, cached
  return *(const bf16x8*)((const char*)g + (row << 9) + kByte);
}
DEV bf16x8 ld_glb_nt(const u16* g, int row, int kByte) {  // streaming variant
  return __builtin_nontemporal_load((const bf16x8*)((const char*)g + (row << 9) + kByte));
}
DEV f32x4 ldx_nt(const float* p) { return __builtin_nontemporal_load((const f32x4*)p); }
DEV u16x8 lds8_nt(const u16* p) { return __builtin_nontemporal_load((const u16x8*)p); }
DEV void st8_nt(u16* p, u16x8 v) { __builtin_nontemporal_store(v, (u16x8*)p); }
DEV void stb8_nt(u16* p, bf16x8 v) { __builtin_nontemporal_store(v, (bf16x8*)p); }
DEV void stf4_nt(float* p, f32x4 v) { __builtin_nontemporal_store(v, (f32x4*)p); }

template <int MI, int NJ>
DEV void zero_acc(f32x4 acc[MI][NJ]) {
#pragma unroll
  for (int i = 0; i < MI; ++i)
#pragma unroll
    for (int j = 0; j < NJ; ++j) {
      acc[i][j][0] = 0.f; acc[i][j][1] = 0.f; acc[i][j][2] = 0.f; acc[i][j][3] = 0.f;
    }
}

// D[m][n] = sum_k P[m][k] * Q[n][k], K=256. MI/NJ = 16x16 tiles per wave.
template <int MI, int NJ, typename LA, typename LB>
DEV void gemmT(LA loadA, LB loadB, f32x4 acc[MI][NJ]) {
#pragma unroll
  for (int kk = 0; kk < 8; ++kk) {
    bf16x8 a[MI], b[NJ];
#pragma unroll
    for (int i = 0; i < MI; ++i) a[i] = loadA(i, kk);
#pragma unroll
    for (int j = 0; j < NJ; ++j) b[j] = loadB(j, kk);
#pragma unroll
    for (int i = 0; i < MI; ++i)
#pragma unroll
      for (int j = 0; j < NJ; ++j)
        acc[i][j] = __builtin_amdgcn_mfma_f32_16x16x32_bf16(a[i], b[j], acc[i][j], 0, 0, 0);
  }
}

#define WAVE_SETUP                  \
  const int tid = threadIdx.x;      \
  const int lane = tid & 63;        \
  const int wave = tid >> 6;        \
  const int wm = wave >> 2;         \
  const int wn = wave & 3;          \
  const int lr = lane & 15;         \
  const int lk = lane >> 4;

// ---------- weight pack: WT[s][n*256+k] = W_s[k*256+n] (+I for s==7) ----------
__global__ void k_pack_all(const float* W0, const float* W1p, const float* W2p,
                           const float* W3p, const float* W4p, const float* W5p,
                           const float* W6p, const float* W7p, u16* __restrict__ WT) {
  int bi = blockIdx.x;
  int wsel = bi >> 8, n = bi & 255;
  const float* W;
  switch (wsel) {
    case 0: W = W0; break; case 1: W = W1p; break; case 2: W = W2p; break;
    case 3: W = W3p; break; case 4: W = W4p; break; case 5: W = W5p; break;
    case 6: W = W6p; break; default: W = W7p; break;
  }
  u16* dst = WT + wsel * 65536;
  int k0 = threadIdx.x * 4;
#pragma unroll
  for (int i = 0; i < 4; ++i) {
    int k = k0 + i;
    float v = __builtin_nontemporal_load(W + k * 256 + n);
    if (wsel == 7 && k == n) v += 1.0f;
    dst[n * 256 + k] = f2b(v);
  }
}

// ---------- att: D[p][c] = sum_q Wa[q][p] X[q][c] (+b_attn[p]); c-half blocks ----------
__global__ __launch_bounds__(512, 4) void k_att(const float* __restrict__ x,
    const u16* __restrict__ WTattn, const float* __restrict__ b_attn,
    u16* __restrict__ att) {
  __shared__ alignas(16) u16 XT[32768];  // [c-half 128][q 256], 64 KiB
  WAVE_SETUP;
  const int ch = blockIdx.x & 1;
  const int t = blockIdx.x >> 1;
  const int d = t & 31, w1 = (t >> 5) & 1, h1 = (t >> 6) & 1, b = t >> 7;
  const int B0 = (((b * 32 + h1 * 16) * 32 + w1 * 16) * 32 + d) * 256;

  for (int i = tid; i < 8192; i += 512) {
    int q = i >> 5;
    int c4 = (i & 31) << 2;
    const f32x4 v = ldx_nt(x + B0 + (q >> 4) * 262144 + (q & 15) * 8192 + ch * 128 + c4);
    XT[lds_off(c4 + 0, q * 2) >> 1] = f2b(v[0]);
    XT[lds_off(c4 + 1, q * 2) >> 1] = f2b(v[1]);
    XT[lds_off(c4 + 2, q * 2) >> 1] = f2b(v[2]);
    XT[lds_off(c4 + 3, q * 2) >> 1] = f2b(v[3]);
  }
  __syncthreads();

  f32x4 acc[8][2];
  zero_acc<8, 2>(acc);
  gemmT<8, 2>(
      [&](int i, int kk) { return ld_glb(WTattn, wm * 128 + i * 16 + lr, kk * 64 + lk * 16); },
      [&](int j, int kk) { return ld_lds(XT, wn * 32 + j * 16 + lr, kk * 64 + lk * 16); },
      acc);

  __syncthreads();  // XT dead; reuse as [p 256][c-half 128] bounce tile (256B pitch)
#pragma unroll
  for (int i = 0; i < 8; ++i)
#pragma unroll
    for (int j = 0; j < 2; ++j)
#pragma unroll
      for (int r = 0; r < 4; ++r) {
        int p = wm * 128 + i * 16 + lk * 4 + r;
        int cl = wn * 32 + j * 16 + lr;
        XT[lds_off256(p, cl * 2) >> 1] = f2b(acc[i][j][r] + b_attn[p]);
      }
  __syncthreads();
  u16* out = att + t * 65536;
  for (int i = tid; i < 4096; i += 512) {
    int p = i >> 4, sB = (i & 15) << 4;
    bf16x8 v = *(const bf16x8*)((const char*)XT + p * 256 + sB);
    int c8l = (sB ^ ((p & 15) << 4)) >> 1;
    stb8_nt(out + p * 256 + ch * 128 + c8l, v);
  }
}

// ---------- k_hw: h and w GEMMs; WTh and WTw each read ONCE per block ----------
// h phase s: B rows 64s..64s+63 of WTh -> pos slab [64s,64s+64) -> h_out stream.
// w phase q: B rows 64q..64q+63 of WTw -> 64 pos rows {p: p%16 in [4q,4q+4)} -> w_out.
__global__ __launch_bounds__(512, 1) void k_hw(const float* __restrict__ x,
    const u16* __restrict__ WTh, const u16* __restrict__ WTw,
    u16* __restrict__ h_out, u16* __restrict__ w_out) {
  __shared__ alignas(16) u16 XS[65536];  // 128 KiB [pos][c]
  __shared__ alignas(16) u16 BB[16384];  // 32 KiB bounce [64][256]
  WAVE_SETUP;
  const int t = blockIdx.x;
  const int d = t & 31, w1 = (t >> 5) & 1, h1 = (t >> 6) & 1, b = t >> 7;
  const int B0 = (((b * 32 + h1 * 16) * 32 + w1 * 16) * 32 + d) * 256;
  u16* h_t = h_out + t * 65536;
  u16* w_t = w_out + t * 65536;

  for (int i = tid; i < 16384; i += 512) {
    int pos = i >> 6, c4 = (i & 63) << 2;
    const f32x4 v = ldx_nt(x + B0 + (pos >> 4) * 262144 + (pos & 15) * 8192 + c4);
    u16x4 pk;
    pk[0] = f2b(v[0]); pk[1] = f2b(v[1]); pk[2] = f2b(v[2]); pk[3] = f2b(v[3]);
    *(u16x4*)((char*)XS + lds_off(pos, c4 * 2)) = pk;
  }
  __syncthreads();

  // ---- h phases: 4 n-chunks, WTh rows disjoint (read once total) ----
  for (int s = 0; s < 4; ++s) {
    f32x4 hacc[8][1];
    zero_acc<8, 1>(hacc);
    gemmT<8, 1>(
        [&](int i, int kk) {
          int k = kk * 32 + lk * 8;
          return *(const bf16x8*)((const char*)XS +
                                  lds_off((k >> 4) * 16 + lr, (wm * 8 + i) * 32 + (k & 15) * 2));
        },
        [&](int j, int kk) { return ld_glb(WTh, s * 64 + wn * 16 + lr, kk * 64 + lk * 16); },
        hacc);
    __syncthreads();  // prev phase's BB reads done
    // element mh=(wm*8+i)*16+lk*4+r, nl=wn*16+lr -> posl=wn*16+lk*4+r, c=(wm*8+i)*16+lr
#pragma unroll
    for (int i = 0; i < 8; ++i)
#pragma unroll
      for (int r = 0; r < 4; ++r)
        BB[lds_off(wn * 16 + lk * 4 + r, ((wm * 8 + i) * 16 + lr) * 2) >> 1] = f2b(hacc[i][0][r]);
    __syncthreads();
    for (int i2 = tid; i2 < 2048; i2 += 512) {
      int posl = i2 >> 5, sB = (i2 & 31) << 4;
      bf16x8 v = *(const bf16x8*)((const char*)BB + posl * 512 + sB);
      int c8 = (sB ^ ((posl & 31) << 4)) >> 1;
      stb8_nt(h_t + (s * 64 + posl) * 256 + c8, v);
    }
  }

  // ---- w phases: 4 n-chunks, WTw rows disjoint (read once total) ----
  for (int q = 0; q < 4; ++q) {
    f32x4 wacc[8][1];
    zero_acc<8, 1>(wacc);
    gemmT<8, 1>(
        [&](int i, int kk) {
          int k = kk * 32 + lk * 8;
          return *(const bf16x8*)((const char*)XS +
                                  lds_off(lr * 16 + (k >> 4), (wm * 8 + i) * 32 + (k & 15) * 2));
        },
        [&](int j, int kk) { return ld_glb(WTw, q * 64 + wn * 16 + lr, kk * 64 + lk * 16); },
        wacc);
    __syncthreads();
    // element mw=(wm*8+i)*16+lk*4+r, nw=q*64+wn*16+lr
    //   pos=(lk*4+r)*16 + 4q+wn, c=(wm*8+i)*16+lr -> BB row rb=(lk*4+r)*4+wn
#pragma unroll
    for (int i = 0; i < 8; ++i)
#pragma unroll
      for (int r = 0; r < 4; ++r)
        BB[lds_off((lk * 4 + r) * 4 + wn, ((wm * 8 + i) * 16 + lr) * 2) >> 1] = f2b(wacc[i][0][r]);
    __syncthreads();
    for (int i2 = tid; i2 < 2048; i2 += 512) {
      int rb = i2 >> 5, sB = (i2 & 31) << 4;
      bf16x8 v = *(const bf16x8*)((const char*)BB + rb * 512 + sB);
      int c8 = (sB ^ ((rb & 31) << 4)) >> 1;
      int pos = (rb >> 2) * 16 + 4 * q + (rb & 3);
      stb8_nt(w_t + pos * 256 + c8, v);
    }
  }
}

// ---------- k_comb: c-GEMM + (h,w,att streams) + W1 + residual -> x1_blk (pos-half) ----------
__global__ __launch_bounds__(512, 2) void k_comb(const float* __restrict__ x,
    const u16* __restrict__ h_out, const u16* __restrict__ w_out, const u16* __restrict__ att,
    const float* __restrict__ bh, const float* __restrict__ bw, const float* __restrict__ bc,
    const u16* __restrict__ WTc, const u16* __restrict__ WT1, const float* __restrict__ b1,
    u16* __restrict__ x1_blk) {
  __shared__ alignas(16) u16 XS[32768];  // 64 KiB x tile [posl 128][c 256]
  __shared__ alignas(16) u16 BB[32768];  // 64 KiB work tile
  WAVE_SETUP;
  const int ph = blockIdx.x & 1;
  const int t = blockIdx.x >> 1;
  const int d = t & 31, w1 = (t >> 5) & 1, h1 = (t >> 6) & 1, b = t >> 7;
  const int B0 = (((b * 32 + h1 * 16) * 32 + w1 * 16) * 32 + d) * 256;
  const u16* h_t = h_out + t * 65536;
  const u16* w_t = w_out + t * 65536;
  const u16* att_t = att + t * 65536;

  // stage XS (bf16) for this pos-half; x read ONCE
  for (int i = tid; i < 8192; i += 512) {
    int posl = i >> 6, c4 = (i & 63) << 2;
    int pos = ph * 128 + posl;
    const f32x4 v = ldx_nt(x + B0 + (pos >> 4) * 262144 + (pos & 15) * 8192 + c4);
    u16x4 pk;
    pk[0] = f2b(v[0]); pk[1] = f2b(v[1]); pk[2] = f2b(v[2]); pk[3] = f2b(v[3]);
    *(u16x4*)((char*)XS + lds_off(posl, c4 * 2)) = pk;
  }
  __syncthreads();

  // c-GEMM (Wc read once per block)
  f32x4 acc[4][4];
  zero_acc<4, 4>(acc);
  gemmT<4, 4>(
      [&](int i, int kk) { return ld_lds(XS, wm * 64 + i * 16 + lr, kk * 64 + lk * 16); },
      [&](int j, int kk) { return ld_glb(WTc, wn * 64 + j * 16 + lr, kk * 64 + lk * 16); },
      acc);
  // BB = acc + bc + bh + bw
#pragma unroll
  for (int i = 0; i < 4; ++i) {
    int lh = ph * 8 + wm * 4 + i;  // (ph*128 + wm*64 + i*16 + ...) >> 4
#pragma unroll
    for (int j = 0; j < 4; ++j) {
      float bcv = bc[wn * 64 + j * 16 + lr];
#pragma unroll
      for (int r = 0; r < 4; ++r) {
        int posl = wm * 64 + i * 16 + lk * 4 + r;
        int n = wn * 64 + j * 16 + lr;
        float v = acc[i][j][r] + bcv + bh[lh * 16 + lr] + bw[(lk * 4 + r) * 16 + lr];
        BB[lds_off(posl, n * 2) >> 1] = f2b(v);
      }
    }
  }
  __syncthreads();

  // streamed: BB = (1+att) * (BB + h + w)
  for (int i2 = tid; i2 < 4096; i2 += 512) {
    int posl = i2 >> 5, c8 = (i2 & 31) << 3;
    int pos = ph * 128 + posl;
    u16x8 hv = lds8_nt(h_t + pos * 256 + c8);
    u16x8 wv = lds8_nt(w_t + pos * 256 + c8);
    u16x8 av = lds8_nt(att_t + pos * 256 + c8);
    u16x8* p = (u16x8*)((char*)BB + lds_off(posl, c8 * 2));
    u16x8 cur = *p, o;
#pragma unroll
    for (int j = 0; j < 8; ++j)
      o[j] = f2b((1.0f + b2f(av[j])) * (b2f(cur[j]) + b2f(hv[j]) + b2f(wv[j])));
    *p = o;
  }
  __syncthreads();

  // W1-GEMM (W1 read once per block)
  zero_acc<4, 4>(acc);
  gemmT<4, 4>(
      [&](int i, int kk) { return ld_lds(BB, wm * 64 + i * 16 + lr, kk * 64 + lk * 16); },
      [&](int j, int kk) { return ld_glb(WT1, wn * 64 + j * 16 + lr, kk * 64 + lk * 16); },
      acc);
  __syncthreads();
  // BB = acc + b1
#pragma unroll
  for (int i = 0; i < 4; ++i)
#pragma unroll
    for (int j = 0; j < 4; ++j) {
      float b1v = b1[wn * 64 + j * 16 + lr];
#pragma unroll
      for (int r = 0; r < 4; ++r) {
        int posl = wm * 64 + i * 16 + lk * 4 + r;
        int n = wn * 64 + j * 16 + lr;
        BB[lds_off(posl, n * 2) >> 1] = f2b(acc[i][j][r] + b1v);
      }
    }
  __syncthreads();

  // x1 = BB + x(bf16 from XS); wide store (t-blocked)
  u16* x1out = x1_blk + t * 65536;
  for (int i2 = tid; i2 < 4096; i2 += 512) {
    int posl = i2 >> 5, sB = (i2 & 31) << 4;
    bf16x8 v = *(const bf16x8*)((const char*)BB + posl * 512 + sB);
    bf16x8 xv = *(const bf16x8*)((const char*)XS + posl * 512 + sB);
    int c8 = (sB ^ ((posl & 31) << 4)) >> 1;
    u16x8 o;
#pragma unroll
    for (int j = 0; j < 8; ++j) o[j] = f2b(b2f((u16)v[j]) + b2f((u16)xv[j]));
    st8_nt(x1out + (ph * 128 + posl) * 256 + c8, o);
  }
}

// ---------- d-block gather GEMM (wlo-half blocks) ----------
__global__ __launch_bounds__(512, 2) void k_d(const u16* __restrict__ x1_blk,
    const u16* __restrict__ WTd, const float* __restrict__ bd, u16* __restrict__ xd) {
  __shared__ alignas(16) u16 XS[32768];  // [R 128][c 256]: R=(wloLoc,ld)
  WAVE_SETUP;
  const int bid = blockIdx.x;
  const int wh = bid & 1, d1 = (bid >> 1) & 1, wb = (bid >> 2) & 1,
            h = (bid >> 3) & 31, b = bid >> 8;
  const int tbase = b * 128 + (h >> 4) * 64 + wb * 32 + d1 * 16;
  const int posbase = (h & 15) * 16 + wh * 8;

  for (int i = tid; i < 4096; i += 512) {
    int Rl = i >> 5;              // wloLoc*16 + ld
    int c8 = (i & 31) << 3;
    int wloLoc = Rl >> 4, ld = Rl & 15;
    const u16x8 v = lds8_nt(x1_blk + (size_t)(tbase + ld) * 65536 +
                            (posbase + wloLoc) * 256 + c8);
    *(u16x8*)((char*)XS + lds_off(Rl, c8 * 2)) = v;
  }
  __syncthreads();

  f32x4 acc[4][4];
  zero_acc<4, 4>(acc);
  // m=(wloLoc,lc) k=(ld,g): A[m][k] = XS[(m>>4)*16+ld][lc*16+g]
  gemmT<4, 4>(
      [&](int i, int kk) {
        int k = kk * 32 + lk * 8;
        int khi = k >> 4, kloB = (k & 15) * 2;
        int mt = wm * 4 + i;
        return *(const bf16x8*)((const char*)XS + lds_off(mt * 16 + khi, lr * 32 + kloB));
      },
      [&](int j, int kk) { return ld_glb(WTd, wn * 64 + j * 16 + lr, kk * 64 + lk * 16); },
      acc);
  __syncthreads();
  // bounce: (mloc,n) -> row=(mloc>>4)*16+(n>>4), col=(mloc&15)*16+(n&15)
#pragma unroll
  for (int i = 0; i < 4; ++i)
#pragma unroll
    for (int j = 0; j < 4; ++j)
#pragma unroll
      for (int r = 0; r < 4; ++r) {
        int mloc = wm * 64 + i * 16 + lk * 4 + r;
        int n = wn * 64 + j * 16 + lr;
        int row = ((mloc >> 4) << 4) + (n >> 4);
        int col = ((mloc & 15) << 4) + (n & 15);
        XS[lds_off(row, col * 2) >> 1] = f2b(acc[i][j][r] + bd[n]);
      }
  __syncthreads();
  const int B0d = (((b * 32 + h) * 32 + wb * 16) * 32 + d1 * 16) * 256;
  for (int i = tid; i < 4096; i += 512) {
    int Rl = i >> 5, sB = (i & 31) << 4;
    bf16x8 v = *(const bf16x8*)((const char*)XS + Rl * 512 + sB);
    int c8 = (sB ^ ((Rl & 31) << 4)) >> 1;
    stb8_nt(xd + B0d + (wh * 8 + (Rl >> 4)) * 8192 + (Rl & 15) * 256 + c8, v);
  }
}

// ---------- fin: x2 = x1 + xd*W2 + b2; out = x2*(W3+I) + b3 (pos-half blocks) ----------
__global__ __launch_bounds__(512, 2) void k_fin(const u16* __restrict__ x1_blk,
    const u16* __restrict__ xd, const u16* __restrict__ WT2, const u16* __restrict__ WT3p,
    const float* __restrict__ b2, const float* __restrict__ b3, float* __restrict__ outp) {
  __shared__ alignas(16) u16 X2[32768];  // [128][256] bf16; later f32 bounce [64][256]
  WAVE_SETUP;
  const int ph = blockIdx.x & 1;
  const int vt = blockIdx.x >> 1;
  const int b = vt >> 7, h = (vt >> 2) & 31, w_hi = vt & 3;
  const size_t base = (size_t)vt * 65536;

  // stage x1 rows into X2 (wide); x1_blk is t-blocked
  for (int i = tid; i < 4096; i += 512) {
    int Rl = i >> 5, c8 = (i & 31) << 3;
    int rglob = ph * 128 + Rl;
    int w = w_hi * 8 + (rglob >> 5), d = rglob & 31;
    int t = b * 128 + (h >> 4) * 64 + (w >> 4) * 32 + d;
    int pos = (h & 15) * 16 + (w & 15);
    const u16x8 v = lds8_nt(x1_blk + (size_t)t * 65536 + pos * 256 + c8);
    *(u16x8*)((char*)X2 + lds_off(Rl, c8 * 2)) = v;
  }

  // GEMM1: xd * W2 (A streamed from global)
  const u16* xd_t = xd + base;
  f32x4 acc[4][4];
  zero_acc<4, 4>(acc);
  gemmT<4, 4>(
      [&](int i, int kk) { return ld_glb_nt(xd_t, ph * 128 + wm * 64 + i * 16 + lr, kk * 64 + lk * 16); },
      [&](int j, int kk) { return ld_glb(WT2, wn * 64 + j * 16 + lr, kk * 64 + lk * 16); },
      acc);
  __syncthreads();

  // X2 = bf16(x1 + acc + b2)
#pragma unroll
  for (int i = 0; i < 4; ++i)
#pragma unroll
    for (int j = 0; j < 4; ++j)
#pragma unroll
      for (int r = 0; r < 4; ++r) {
        int mloc = wm * 64 + i * 16 + lk * 4 + r;
        int n = wn * 64 + j * 16 + lr;
        int off = lds_off(mloc, n * 2) >> 1;
        X2[off] = f2b(b2f(X2[off]) + acc[i][j][r] + b2[n]);
      }
  __syncthreads();

  // GEMM2: X2 * (W3+I)
  zero_acc<4, 4>(acc);
  gemmT<4, 4>(
      [&](int i, int kk) { return ld_lds(X2, wm * 64 + i * 16 + lr, kk * 64 + lk * 16); },
      [&](int j, int kk) { return ld_glb(WT3p, wn * 64 + j * 16 + lr, kk * 64 + lk * 16); },
      acc);

  // fp32 output via 2-round LDS bounce (64 rows each), float4 stores
  float* X2f = (float*)X2;
#pragma unroll
  for (int half = 0; half < 2; ++half) {
    __syncthreads();
    if (wm == half) {
#pragma unroll
      for (int i = 0; i < 4; ++i)
#pragma unroll
        for (int j = 0; j < 4; ++j)
#pragma unroll
          for (int r = 0; r < 4; ++r) {
            int row = i * 16 + lk * 4 + r;
            int n = wn * 64 + j * 16 + lr;
            X2f[row * 256 + n] = acc[i][j][r] + b3[n];
          }
    }
    __syncthreads();
    for (int i = tid; i < 4096; i += 512) {
      int row = i >> 6, c4 = (i & 63) << 2;
      f32x4 v = *(const f32x4*)(X2f + row * 256 + c4);
      stf4_nt(outp + base + (size_t)(ph * 128 + half * 64 + row) * 256 + c4, v);
    }
  }
}

extern "C" void kernel_launch(void* const* d_in, const int* in_sizes, int n_in,
                              void* d_out, int out_size, void* d_ws, size_t ws_size,
                              hipStream_t stream) {
  (void)in_sizes; (void)n_in; (void)out_size; (void)ws_size;
  const float* x      = (const float*)d_in[0];
  const float* W_h    = (const float*)d_in[1];
  const float* b_h    = (const float*)d_in[2];
  const float* W_w    = (const float*)d_in[3];
  const float* b_w    = (const float*)d_in[4];
  const float* W_c    = (const float*)d_in[5];
  const float* b_c    = (const float*)d_in[6];
  const float* W_d    = (const float*)d_in[7];
  const float* b_d    = (const float*)d_in[8];
  const float* W_attn = (const float*)d_in[9];
  const float* b_attn = (const float*)d_in[10];
  const float* W_1    = (const float*)d_in[11];
  const float* b_1    = (const float*)d_in[12];
  const float* W_2    = (const float*)d_in[13];
  const float* b_2    = (const float*)d_in[14];
  const float* W_3    = (const float*)d_in[15];
  const float* b_3    = (const float*)d_in[16];
  float* outp = (float*)d_out;

  u16* WT = (u16*)d_ws;             // 8 * 65536 bf16 (1 MiB)
  u16* R1 = WT + 8 * 65536;         // 64 MiB: x1_blk (t-blocked bf16)
  u16* R2 = R1 + 33554432;          // 64 MiB: att scratch -> xd
  u16* HOS = (u16*)d_out;           // h stream: first 64 MiB of d_out
  u16* WOS = HOS + 33554432;        // w stream: second 64 MiB of d_out

  // slots: 0:h 1:w 2:c 3:attn 4:W1 5:Wd 6:W2 7:W3(+I)
  k_pack_all<<<2048, 64, 0, stream>>>(W_h, W_w, W_c, W_attn, W_1, W_d, W_2, W_3, WT);

  k_att <<<1024, 512, 0, stream>>>(x, WT + 3 * 65536, b_attn, R2);
  k_hw  <<<512, 512, 0, stream>>>(x, WT + 0 * 65536, WT + 1 * 65536, HOS, WOS);
  k_comb<<<1024, 512, 0, stream>>>(x, HOS, WOS, R2, b_h, b_w, b_c,
                                   WT + 2 * 65536, WT + 4 * 65536, b_1, R1);
  k_d   <<<1024, 512, 0, stream>>>(R1, WT + 5 * 65536, b_d, R2);
  k_fin <<<1024, 512, 0, stream>>>(R1, R2, WT + 6 * 65536, WT + 7 * 65536, b_2, b_3, outp);
}

// Round 9
// 546.780 us; speedup vs baseline: 1.4323x; 1.1049x over previous
//
#include <hip/hip_runtime.h>

// MLPP: 8x 256x256 GEMMs over gathered views of x[4,32,32,32,256] (fp32 in/out).
// pack -> k_att (x fp32 -> att + xbf bf16 copy) -> k_hw (xbf -> h,w streams in d_out)
//      -> k_comb (xbf + h/w/att streams + W1 + residual -> x1 in x-layout, overlaying xbf)
//      -> k_d (x1 -> xd) -> k_fin (x1 linear + xd -> out, overwriting h/w)
// x fp32 read ONCE (k_att). nt hints only on never-re-read data (x in, out final).

typedef __attribute__((ext_vector_type(8))) short bf16x8;
typedef __attribute__((ext_vector_type(8))) unsigned short u16x8;
typedef __attribute__((ext_vector_type(4))) float f32x4;
typedef __attribute__((ext_vector_type(4))) unsigned short u16x4;
typedef unsigned short u16;
typedef unsigned int u32;

#define DEV __device__ __forceinline__

DEV u16 f2b(float f) {  // fp32 -> bf16 RNE
  union { float f; u32 u; } v; v.f = f;
  u32 r = v.u + 0x7FFFu + ((v.u >> 16) & 1u);
  return (u16)(r >> 16);
}
DEV float b2f(u16 b) {
  union { u32 u; float f; } v; v.u = ((u32)b) << 16; return v.f;
}

// 512B-pitch LDS tiles, XOR swizzle over 16B slots (32 slots/row).
DEV int lds_off(int row, int colByte) {
  return (row << 9) + (colByte ^ ((row & 31) << 4));
}
// 256B-pitch tiles (16 slots/row).
DEV int lds_off256(int row, int colByte) {
  return (row << 8) + (colByte ^ ((row & 15) << 4));
}
DEV bf16x8 ld_lds(const u16* lds, int row, int colByte) {
  return *(const bf16x8*)((const char*)lds + lds_off(row, colByte));
}
DEV bf16x8 ld_glb(const u16* g, int row, int kByte) {  // row-major [.][256] bf16, cached
  return *(const bf16x8*)((const char*)g + (row << 9) + kByte);
}
DEV f32x4 ldx_nt(const float* p) { return __builtin_nontemporal_load((const f32x4*)p); }
DEV void stf4_nt(float* p, f32x4 v) { __builtin_nontemporal_store(v, (f32x4*)p); }

template <int MI, int NJ>
DEV void zero_acc(f32x4 acc[MI][NJ]) {
#pragma unroll
  for (int i = 0; i < MI; ++i)
#pragma unroll
    for (int j = 0; j < NJ; ++j) {
      acc[i][j][0] = 0.f; acc[i][j][1] = 0.f; acc[i][j][2] = 0.f; acc[i][j][3] = 0.f;
    }
}

// D[m][n] = sum_k P[m][k] * Q[n][k], K=256. MI/NJ = 16x16 tiles per wave.
template <int MI, int NJ, typename LA, typename LB>
DEV void gemmT(LA loadA, LB loadB, f32x4 acc[MI][NJ]) {
#pragma unroll
  for (int kk = 0; kk < 8; ++kk) {
    bf16x8 a[MI], b[NJ];
#pragma unroll
    for (int i = 0; i < MI; ++i) a[i] = loadA(i, kk);
#pragma unroll
    for (int j = 0; j < NJ; ++j) b[j] = loadB(j, kk);
#pragma unroll
    for (int i = 0; i < MI; ++i)
#pragma unroll
      for (int j = 0; j < NJ; ++j)
        acc[i][j] = __builtin_amdgcn_mfma_f32_16x16x32_bf16(a[i], b[j], acc[i][j], 0, 0, 0);
  }
}

#define WAVE_SETUP                  \
  const int tid = threadIdx.x;      \
  const int lane = tid & 63;        \
  const int wave = tid >> 6;        \
  const int wm = wave >> 2;         \
  const int wn = wave & 3;          \
  const int lr = lane & 15;         \
  const int lk = lane >> 4;

// ---------- weight pack: WT[s][n*256+k] = W_s[k*256+n] (+I for s==7) ----------
__global__ void k_pack_all(const float* W0, const float* W1p, const float* W2p,
                           const float* W3p, const float* W4p, const float* W5p,
                           const float* W6p, const float* W7p, u16* __restrict__ WT) {
  int bi = blockIdx.x;
  int wsel = bi >> 8, n = bi & 255;
  const float* W;
  switch (wsel) {
    case 0: W = W0; break; case 1: W = W1p; break; case 2: W = W2p; break;
    case 3: W = W3p; break; case 4: W = W4p; break; case 5: W = W5p; break;
    case 6: W = W6p; break; default: W = W7p; break;
  }
  u16* dst = WT + wsel * 65536;
  int k0 = threadIdx.x * 4;
#pragma unroll
  for (int i = 0; i < 4; ++i) {
    int k = k0 + i;
    float v = __builtin_nontemporal_load(W + k * 256 + n);
    if (wsel == 7 && k == n) v += 1.0f;
    dst[n * 256 + k] = f2b(v);
  }
}

// ---------- att: D[p][c] = sum_q Wa[q][p] X[q][c] (+b_attn[p]); also emits xbf ----------
__global__ __launch_bounds__(512, 4) void k_att(const float* __restrict__ x,
    const u16* __restrict__ WTattn, const float* __restrict__ b_attn,
    u16* __restrict__ att, u16* __restrict__ xbf) {
  __shared__ alignas(16) u16 XT[32768];  // [c-half 128][q 256], 64 KiB
  WAVE_SETUP;
  const int ch = blockIdx.x & 1;
  const int t = blockIdx.x >> 1;
  const int d = t & 31, w1 = (t >> 5) & 1, h1 = (t >> 6) & 1, b = t >> 7;
  const int B0 = (((b * 32 + h1 * 16) * 32 + w1 * 16) * 32 + d) * 256;

  for (int i = tid; i < 8192; i += 512) {
    int q = i >> 5;
    int c4 = (i & 31) << 2;
    const int gofs = B0 + (q >> 4) * 262144 + (q & 15) * 8192 + ch * 128 + c4;
    const f32x4 v = ldx_nt(x + gofs);
    u16x4 pk;
    pk[0] = f2b(v[0]); pk[1] = f2b(v[1]); pk[2] = f2b(v[2]); pk[3] = f2b(v[3]);
    XT[lds_off(c4 + 0, q * 2) >> 1] = pk[0];
    XT[lds_off(c4 + 1, q * 2) >> 1] = pk[1];
    XT[lds_off(c4 + 2, q * 2) >> 1] = pk[2];
    XT[lds_off(c4 + 3, q * 2) >> 1] = pk[3];
    *(u16x4*)(xbf + gofs) = pk;   // bf16 copy of x, x-layout
  }
  __syncthreads();

  f32x4 acc[8][2];
  zero_acc<8, 2>(acc);
  gemmT<8, 2>(
      [&](int i, int kk) { return ld_glb(WTattn, wm * 128 + i * 16 + lr, kk * 64 + lk * 16); },
      [&](int j, int kk) { return ld_lds(XT, wn * 32 + j * 16 + lr, kk * 64 + lk * 16); },
      acc);

  __syncthreads();  // XT dead; reuse as [p 256][c-half 128] bounce tile (256B pitch)
#pragma unroll
  for (int i = 0; i < 8; ++i)
#pragma unroll
    for (int j = 0; j < 2; ++j)
#pragma unroll
      for (int r = 0; r < 4; ++r) {
        int p = wm * 128 + i * 16 + lk * 4 + r;
        int cl = wn * 32 + j * 16 + lr;
        XT[lds_off256(p, cl * 2) >> 1] = f2b(acc[i][j][r] + b_attn[p]);
      }
  __syncthreads();
  u16* out = att + t * 65536;
  for (int i = tid; i < 4096; i += 512) {
    int p = i >> 4, sB = (i & 15) << 4;
    bf16x8 v = *(const bf16x8*)((const char*)XT + p * 256 + sB);
    int c8l = (sB ^ ((p & 15) << 4)) >> 1;
    *(bf16x8*)(out + p * 256 + ch * 128 + c8l) = v;
  }
}

// ---------- k_hw: h and w GEMMs from xbf; WTh and WTw each read ONCE per block ----------
__global__ __launch_bounds__(512, 1) void k_hw(const u16* __restrict__ xbf,
    const u16* __restrict__ WTh, const u16* __restrict__ WTw,
    u16* __restrict__ h_out, u16* __restrict__ w_out) {
  __shared__ alignas(16) u16 XS[65536];  // 128 KiB [pos][c]
  __shared__ alignas(16) u16 BB[16384];  // 32 KiB bounce [64][256]
  WAVE_SETUP;
  const int t = blockIdx.x;
  const int d = t & 31, w1 = (t >> 5) & 1, h1 = (t >> 6) & 1, b = t >> 7;
  const int B0 = (((b * 32 + h1 * 16) * 32 + w1 * 16) * 32 + d) * 256;
  u16* h_t = h_out + t * 65536;
  u16* w_t = w_out + t * 65536;

  for (int i = tid; i < 8192; i += 512) {
    int pos = i >> 5, c8 = (i & 31) << 3;
    u16x8 v = *(const u16x8*)(xbf + B0 + (pos >> 4) * 262144 + (pos & 15) * 8192 + c8);
    *(u16x8*)((char*)XS + lds_off(pos, c8 * 2)) = v;
  }
  __syncthreads();

  // ---- h phases: 4 n-chunks, WTh rows disjoint (read once total) ----
  for (int s = 0; s < 4; ++s) {
    f32x4 hacc[8][1];
    zero_acc<8, 1>(hacc);
    gemmT<8, 1>(
        [&](int i, int kk) {
          int k = kk * 32 + lk * 8;
          return *(const bf16x8*)((const char*)XS +
                                  lds_off((k >> 4) * 16 + lr, (wm * 8 + i) * 32 + (k & 15) * 2));
        },
        [&](int j, int kk) { return ld_glb(WTh, s * 64 + wn * 16 + lr, kk * 64 + lk * 16); },
        hacc);
    __syncthreads();  // prev phase's BB reads done
    // element mh=(wm*8+i)*16+lk*4+r, nl=wn*16+lr -> posl=wn*16+lk*4+r, c=(wm*8+i)*16+lr
#pragma unroll
    for (int i = 0; i < 8; ++i)
#pragma unroll
      for (int r = 0; r < 4; ++r)
        BB[lds_off(wn * 16 + lk * 4 + r, ((wm * 8 + i) * 16 + lr) * 2) >> 1] = f2b(hacc[i][0][r]);
    __syncthreads();
    for (int i2 = tid; i2 < 2048; i2 += 512) {
      int posl = i2 >> 5, sB = (i2 & 31) << 4;
      bf16x8 v = *(const bf16x8*)((const char*)BB + posl * 512 + sB);
      int c8 = (sB ^ ((posl & 31) << 4)) >> 1;
      *(bf16x8*)(h_t + (s * 64 + posl) * 256 + c8) = v;
    }
  }

  // ---- w phases: 4 n-chunks, WTw rows disjoint (read once total) ----
  for (int q = 0; q < 4; ++q) {
    f32x4 wacc[8][1];
    zero_acc<8, 1>(wacc);
    gemmT<8, 1>(
        [&](int i, int kk) {
          int k = kk * 32 + lk * 8;
          return *(const bf16x8*)((const char*)XS +
                                  lds_off(lr * 16 + (k >> 4), (wm * 8 + i) * 32 + (k & 15) * 2));
        },
        [&](int j, int kk) { return ld_glb(WTw, q * 64 + wn * 16 + lr, kk * 64 + lk * 16); },
        wacc);
    __syncthreads();
    // element mw=(wm*8+i)*16+lk*4+r, nw=q*64+wn*16+lr
    //   pos=(lk*4+r)*16 + 4q+wn, c=(wm*8+i)*16+lr -> BB row rb=(lk*4+r)*4+wn
#pragma unroll
    for (int i = 0; i < 8; ++i)
#pragma unroll
      for (int r = 0; r < 4; ++r)
        BB[lds_off((lk * 4 + r) * 4 + wn, ((wm * 8 + i) * 16 + lr) * 2) >> 1] = f2b(wacc[i][0][r]);
    __syncthreads();
    for (int i2 = tid; i2 < 2048; i2 += 512) {
      int rb = i2 >> 5, sB = (i2 & 31) << 4;
      bf16x8 v = *(const bf16x8*)((const char*)BB + rb * 512 + sB);
      int c8 = (sB ^ ((rb & 31) << 4)) >> 1;
      int pos = (rb >> 2) * 16 + 4 * q + (rb & 3);
      *(bf16x8*)(w_t + pos * 256 + c8) = v;
    }
  }
}

// ---------- k_comb: c-GEMM + (h,w,att streams) + W1 + residual -> x1 (x-layout) ----------
__global__ __launch_bounds__(512, 2) void k_comb(const u16* __restrict__ xbf,
    const u16* __restrict__ h_out, const u16* __restrict__ w_out, const u16* __restrict__ att,
    const float* __restrict__ bh, const float* __restrict__ bw, const float* __restrict__ bc,
    const u16* __restrict__ WTc, const u16* __restrict__ WT1, const float* __restrict__ b1,
    u16* __restrict__ x1) {
  __shared__ alignas(16) u16 XS[32768];  // 64 KiB x tile [posl 128][c 256]
  __shared__ alignas(16) u16 BB[32768];  // 64 KiB work tile
  WAVE_SETUP;
  const int ph = blockIdx.x & 1;
  const int t = blockIdx.x >> 1;
  const int d = t & 31, w1 = (t >> 5) & 1, h1 = (t >> 6) & 1, b = t >> 7;
  const int B0 = (((b * 32 + h1 * 16) * 32 + w1 * 16) * 32 + d) * 256;
  const u16* h_t = h_out + t * 65536;
  const u16* w_t = w_out + t * 65536;
  const u16* att_t = att + t * 65536;

  // stage XS from xbf (wide, coalesced)
  for (int i = tid; i < 4096; i += 512) {
    int posl = i >> 5, c8 = (i & 31) << 3;
    int pos = ph * 128 + posl;
    u16x8 v = *(const u16x8*)(xbf + B0 + (pos >> 4) * 262144 + (pos & 15) * 8192 + c8);
    *(u16x8*)((char*)XS + lds_off(posl, c8 * 2)) = v;
  }
  __syncthreads();

  // c-GEMM (Wc read once per block)
  f32x4 acc[4][4];
  zero_acc<4, 4>(acc);
  gemmT<4, 4>(
      [&](int i, int kk) { return ld_lds(XS, wm * 64 + i * 16 + lr, kk * 64 + lk * 16); },
      [&](int j, int kk) { return ld_glb(WTc, wn * 64 + j * 16 + lr, kk * 64 + lk * 16); },
      acc);
  // BB = acc + bc + bh + bw
#pragma unroll
  for (int i = 0; i < 4; ++i) {
    int lh = ph * 8 + wm * 4 + i;  // (ph*128 + wm*64 + i*16 + ...) >> 4
#pragma unroll
    for (int j = 0; j < 4; ++j) {
      float bcv = bc[wn * 64 + j * 16 + lr];
#pragma unroll
      for (int r = 0; r < 4; ++r) {
        int posl = wm * 64 + i * 16 + lk * 4 + r;
        int n = wn * 64 + j * 16 + lr;
        float v = acc[i][j][r] + bcv + bh[lh * 16 + lr] + bw[(lk * 4 + r) * 16 + lr];
        BB[lds_off(posl, n * 2) >> 1] = f2b(v);
      }
    }
  }
  __syncthreads();

  // streamed: BB = (1+att) * (BB + h + w)
  for (int i2 = tid; i2 < 4096; i2 += 512) {
    int posl = i2 >> 5, c8 = (i2 & 31) << 3;
    int pos = ph * 128 + posl;
    u16x8 hv = *(const u16x8*)(h_t + pos * 256 + c8);
    u16x8 wv = *(const u16x8*)(w_t + pos * 256 + c8);
    u16x8 av = *(const u16x8*)(att_t + pos * 256 + c8);
    u16x8* p = (u16x8*)((char*)BB + lds_off(posl, c8 * 2));
    u16x8 cur = *p, o;
#pragma unroll
    for (int j = 0; j < 8; ++j)
      o[j] = f2b((1.0f + b2f(av[j])) * (b2f(cur[j]) + b2f(hv[j]) + b2f(wv[j])));
    *p = o;
  }
  __syncthreads();

  // W1-GEMM (W1 read once per block)
  zero_acc<4, 4>(acc);
  gemmT<4, 4>(
      [&](int i, int kk) { return ld_lds(BB, wm * 64 + i * 16 + lr, kk * 64 + lk * 16); },
      [&](int j, int kk) { return ld_glb(WT1, wn * 64 + j * 16 + lr, kk * 64 + lk * 16); },
      acc);
  __syncthreads();
  // BB = acc + b1
#pragma unroll
  for (int i = 0; i < 4; ++i)
#pragma unroll
    for (int j = 0; j < 4; ++j) {
      float b1v = b1[wn * 64 + j * 16 + lr];
#pragma unroll
      for (int r = 0; r < 4; ++r) {
        int posl = wm * 64 + i * 16 + lk * 4 + r;
        int n = wn * 64 + j * 16 + lr;
        BB[lds_off(posl, n * 2) >> 1] = f2b(acc[i][j][r] + b1v);
      }
    }
  __syncthreads();

  // x1 = BB + x(bf16 from XS); wide store, x-layout (block-local overlay of xbf)
  for (int i2 = tid; i2 < 4096; i2 += 512) {
    int posl = i2 >> 5, sB = (i2 & 31) << 4;
    bf16x8 v = *(const bf16x8*)((const char*)BB + posl * 512 + sB);
    bf16x8 xv = *(const bf16x8*)((const char*)XS + posl * 512 + sB);
    int c8 = (sB ^ ((posl & 31) << 4)) >> 1;
    int pos = ph * 128 + posl;
    u16x8 o;
#pragma unroll
    for (int j = 0; j < 8; ++j) o[j] = f2b(b2f((u16)v[j]) + b2f((u16)xv[j]));
    *(u16x8*)(x1 + B0 + (pos >> 4) * 262144 + (pos & 15) * 8192 + c8) = o;
  }
}

// ---------- d-block gather GEMM (wlo-half blocks); x1 in x-layout ----------
__global__ __launch_bounds__(512, 2) void k_d(const u16* __restrict__ x1,
    const u16* __restrict__ WTd, const float* __restrict__ bd, u16* __restrict__ xd) {
  __shared__ alignas(16) u16 XS[32768];  // [R 128][c 256]: R=(wloLoc,ld)
  WAVE_SETUP;
  const int bid = blockIdx.x;
  const int wh = bid & 1, d1 = (bid >> 1) & 1, wb = (bid >> 2) & 1,
            h = (bid >> 3) & 31, b = bid >> 8;
  const int W0 = (b * 32 + h) * 32 + wb * 16 + wh * 8;

  for (int i = tid; i < 4096; i += 512) {
    int Rl = i >> 5;              // wloLoc*16 + ld
    int c8 = (i & 31) << 3;
    int wloLoc = Rl >> 4, ld = Rl & 15;
    const u16x8 v = *(const u16x8*)(x1 + (size_t)(W0 + wloLoc) * 8192 +
                                    (d1 * 16 + ld) * 256 + c8);
    *(u16x8*)((char*)XS + lds_off(Rl, c8 * 2)) = v;
  }
  __syncthreads();

  f32x4 acc[4][4];
  zero_acc<4, 4>(acc);
  // m=(wloLoc,lc) k=(ld,g): A[m][k] = XS[(m>>4)*16+ld][lc*16+g]
  gemmT<4, 4>(
      [&](int i, int kk) {
        int k = kk * 32 + lk * 8;
        int khi = k >> 4, kloB = (k & 15) * 2;
        int mt = wm * 4 + i;
        return *(const bf16x8*)((const char*)XS + lds_off(mt * 16 + khi, lr * 32 + kloB));
      },
      [&](int j, int kk) { return ld_glb(WTd, wn * 64 + j * 16 + lr, kk * 64 + lk * 16); },
      acc);
  __syncthreads();
  // bounce: (mloc,n) -> row=(mloc>>4)*16+(n>>4), col=(mloc&15)*16+(n&15)
#pragma unroll
  for (int i = 0; i < 4; ++i)
#pragma unroll
    for (int j = 0; j < 4; ++j)
#pragma unroll
      for (int r = 0; r < 4; ++r) {
        int mloc = wm * 64 + i * 16 + lk * 4 + r;
        int n = wn * 64 + j * 16 + lr;
        int row = ((mloc >> 4) << 4) + (n >> 4);
        int col = ((mloc & 15) << 4) + (n & 15);
        XS[lds_off(row, col * 2) >> 1] = f2b(acc[i][j][r] + bd[n]);
      }
  __syncthreads();
  const int B0d = (((b * 32 + h) * 32 + wb * 16) * 32 + d1 * 16) * 256;
  for (int i = tid; i < 4096; i += 512) {
    int Rl = i >> 5, sB = (i & 31) << 4;
    bf16x8 v = *(const bf16x8*)((const char*)XS + Rl * 512 + sB);
    int c8 = (sB ^ ((Rl & 31) << 4)) >> 1;
    *(bf16x8*)(xd + B0d + (wh * 8 + (Rl >> 4)) * 8192 + (Rl & 15) * 256 + c8) = v;
  }
}

// ---------- fin: x2 = x1 + xd*W2 + b2; out = x2*(W3+I) + b3 (pos-half blocks) ----------
__global__ __launch_bounds__(512, 2) void k_fin(const u16* __restrict__ x1,
    const u16* __restrict__ xd, const u16* __restrict__ WT2, const u16* __restrict__ WT3p,
    const float* __restrict__ b2, const float* __restrict__ b3, float* __restrict__ outp) {
  __shared__ alignas(16) u16 X2[32768];  // [128][256] bf16; later f32 bounce [64][256]
  WAVE_SETUP;
  const int ph = blockIdx.x & 1;
  const int vt = blockIdx.x >> 1;
  const size_t base = (size_t)vt * 65536;

  // stage x1 rows into X2 — LINEAR (x1 is x-layout, base-aligned per vt)
  for (int i = tid; i < 4096; i += 512) {
    int Rl = i >> 5, c8 = (i & 31) << 3;
    const u16x8 v = *(const u16x8*)(x1 + base + (size_t)(ph * 128 + Rl) * 256 + c8);
    *(u16x8*)((char*)X2 + lds_off(Rl, c8 * 2)) = v;
  }

  // GEMM1: xd * W2 (A from global, L3-resident)
  const u16* xd_t = xd + base;
  f32x4 acc[4][4];
  zero_acc<4, 4>(acc);
  gemmT<4, 4>(
      [&](int i, int kk) { return ld_glb(xd_t, ph * 128 + wm * 64 + i * 16 + lr, kk * 64 + lk * 16); },
      [&](int j, int kk) { return ld_glb(WT2, wn * 64 + j * 16 + lr, kk * 64 + lk * 16); },
      acc);
  __syncthreads();

  // X2 = bf16(x1 + acc + b2)
#pragma unroll
  for (int i = 0; i < 4; ++i)
#pragma unroll
    for (int j = 0; j < 4; ++j)
#pragma unroll
      for (int r = 0; r < 4; ++r) {
        int mloc = wm * 64 + i * 16 + lk * 4 + r;
        int n = wn * 64 + j * 16 + lr;
        int off = lds_off(mloc, n * 2) >> 1;
        X2[off] = f2b(b2f(X2[off]) + acc[i][j][r] + b2[n]);
      }
  __syncthreads();

  // GEMM2: X2 * (W3+I)
  zero_acc<4, 4>(acc);
  gemmT<4, 4>(
      [&](int i, int kk) { return ld_lds(X2, wm * 64 + i * 16 + lr, kk * 64 + lk * 16); },
      [&](int j, int kk) { return ld_glb(WT3p, wn * 64 + j * 16 + lr, kk * 64 + lk * 16); },
      acc);

  // fp32 output via 2-round LDS bounce (64 rows each), float4 nt stores
  float* X2f = (float*)X2;
#pragma unroll
  for (int half = 0; half < 2; ++half) {
    __syncthreads();
    if (wm == half) {
#pragma unroll
      for (int i = 0; i < 4; ++i)
#pragma unroll
        for (int j = 0; j < 4; ++j)
#pragma unroll
          for (int r = 0; r < 4; ++r) {
            int row = i * 16 + lk * 4 + r;
            int n = wn * 64 + j * 16 + lr;
            X2f[row * 256 + n] = acc[i][j][r] + b3[n];
          }
    }
    __syncthreads();
    for (int i = tid; i < 4096; i += 512) {
      int row = i >> 6, c4 = (i & 63) << 2;
      f32x4 v = *(const f32x4*)(X2f + row * 256 + c4);
      stf4_nt(outp + base + (size_t)(ph * 128 + half * 64 + row) * 256 + c4, v);
    }
  }
}

extern "C" void kernel_launch(void* const* d_in, const int* in_sizes, int n_in,
                              void* d_out, int out_size, void* d_ws, size_t ws_size,
                              hipStream_t stream) {
  (void)in_sizes; (void)n_in; (void)out_size; (void)ws_size;
  const float* x      = (const float*)d_in[0];
  const float* W_h    = (const float*)d_in[1];
  const float* b_h    = (const float*)d_in[2];
  const float* W_w    = (const float*)d_in[3];
  const float* b_w    = (const float*)d_in[4];
  const float* W_c    = (const float*)d_in[5];
  const float* b_c    = (const float*)d_in[6];
  const float* W_d    = (const float*)d_in[7];
  const float* b_d    = (const float*)d_in[8];
  const float* W_attn = (const float*)d_in[9];
  const float* b_attn = (const float*)d_in[10];
  const float* W_1    = (const float*)d_in[11];
  const float* b_1    = (const float*)d_in[12];
  const float* W_2    = (const float*)d_in[13];
  const float* b_2    = (const float*)d_in[14];
  const float* W_3    = (const float*)d_in[15];
  const float* b_3    = (const float*)d_in[16];
  float* outp = (float*)d_out;

  u16* WT = (u16*)d_ws;             // 8 * 65536 bf16 (1 MiB)
  u16* R1 = WT + 8 * 65536;         // 64 MiB: xbf (x-layout) -> x1 (x-layout, block-local overlay)
  u16* R2 = R1 + 33554432;          // 64 MiB: att scratch -> xd
  u16* HOS = (u16*)d_out;           // h stream: first 64 MiB of d_out (dead after k_comb)
  u16* WOS = HOS + 33554432;        // w stream: second 64 MiB of d_out (dead after k_comb)

  // slots: 0:h 1:w 2:c 3:attn 4:W1 5:Wd 6:W2 7:W3(+I)
  k_pack_all<<<2048, 64, 0, stream>>>(W_h, W_w, W_c, W_attn, W_1, W_d, W_2, W_3, WT);

  k_att <<<1024, 512, 0, stream>>>(x, WT + 3 * 65536, b_attn, R2, R1);
  k_hw  <<<512, 512, 0, stream>>>(R1, WT + 0 * 65536, WT + 1 * 65536, HOS, WOS);
  k_comb<<<1024, 512, 0, stream>>>(R1, HOS, WOS, R2, b_h, b_w, b_c,
                                   WT + 2 * 65536, WT + 4 * 65536, b_1, R1);
  k_d   <<<1024, 512, 0, stream>>>(R1, WT + 5 * 65536, b_d, R2);
  k_fin <<<1024, 512, 0, stream>>>(R1, R2, WT + 6 * 65536, WT + 7 * 65536, b_2, b_3, outp);
}